// Round 6
// baseline (99.999 us; speedup 1.0000x reference)
//
#include <hip/hip_runtime.h>
#include <math.h>

// Problem constants (from reference):
//   vol: (B=1, C=1, W=96, H=96, D=64) float32, row-major -> vol[(x*96+y)*64+z]
//   out: (B,C,U=96,A=90,V=64) float32 -> out[(u*90+a)*64+v]
//   k[v] = v identically (V=D=64, SV=SD=1), so depth slice index == lane.
namespace {
constexpr int NA = 90, NU = 96, NV = 64, NW = 96, NH = 96, ND = 64;
constexpr int NRAY    = NA * NU;      // 8640
constexpr int NSTEPS  = NH + NW + 2;  // 194
constexpr int NSP_L   = 201;          // LDS row entries: bank stride 402 dwords
                                      // == 18 mod 32, gcd(18,32)=2 -> 16 banks,
                                      // 4 lanes/bank = 4-way (~1.6x, near-free)
constexpr int GSTRIDE = 208;          // global row entries: 1664 B, 16B-aligned
constexpr int TTILE   = 64;           // rays per trace block (one full wave traces)
constexpr int NTBLK   = NRAY / TTILE; // 135 trace blocks
constexpr int GRPB    = 4;            // rays per gather block (4 waves)
constexpr int NGBLK   = NRAY / GRPB;  // 2160 gather blocks
}

// ---------------------------------------------------------------------------
// Kernel A: trace. Wave 0's 64 lanes trace 64 rays into LDS; then all 8
// waves copy LDS -> global in RAY-CONTIGUOUS layout with coalesced stores.
// Diagnostic intent: A's dur_us isolates the trace-chain cost that R2-R5
// could never attribute (everything landed at ~45-50us regardless of shape).
// Entry packed as float2: .x = __int_as_float(BYTE offset into vol), .y = weight.
// ---------------------------------------------------------------------------
__global__ __launch_bounds__(512)
void trace_kernel(float2* __restrict__ ents, int* __restrict__ counts)
{
    __shared__ float2 sE[TTILE][NSP_L];   // 103 KB

    const int tid  = threadIdx.x;
    const int tile = blockIdx.x;          // 0..134

    if (tid < 64) {
        const int rl  = tid;
        const int ray = tile * TTILE + rl;   // a*96 + u
        const int a = ray / NU;
        const int u = ray - a * NU;

        const float EPSf = 1e-12f;
        const float INF  = __builtin_inff();
        const float DIAG = 1.41421356237309514547f;

        const float ang = (float)a * (float)(3.14159265358979323846 / 90.0);
        const float dx = (float)cos((double)ang);
        const float dy = (float)sin((double)ang);
        const float uu = (float)u - 47.5f;
        const float x0 = __fmul_rn(-uu, dy);
        const float y0 = __fmul_rn( uu, dx);

        const float xmin = -47.5f, xmax = 47.5f;
        const float ymin = -47.5f, ymax = 47.5f;

        float tx0, tx1;
        {
            const bool par = fabsf(dx) < EPSf;
            const float safe = par ? 1.0f : dx;
            const float t0 = __fdiv_rn(xmin - x0, safe);
            const float t1 = __fdiv_rn(xmax - x0, safe);
            const float lo = fminf(t0, t1), hi = fmaxf(t0, t1);
            const bool inside = (x0 >= xmin) && (x0 <= xmax);
            tx0 = par ? (inside ? -INF : INF) : lo;
            tx1 = par ? (inside ?  INF : -INF) : hi;
        }
        float ty0, ty1;
        {
            const bool par = fabsf(dy) < EPSf;
            const float safe = par ? 1.0f : dy;
            const float t0 = __fdiv_rn(ymin - y0, safe);
            const float t1 = __fdiv_rn(ymax - y0, safe);
            const float lo = fminf(t0, t1), hi = fmaxf(t0, t1);
            const bool inside = (y0 >= ymin) && (y0 <= ymax);
            ty0 = par ? (inside ? -INF : INF) : lo;
            ty1 = par ? (inside ?  INF : -INF) : hi;
        }

        const float t_entry = fmaxf(tx0, ty0);
        const float t_exit  = fminf(tx1, ty1);
        bool  alive = t_entry < t_exit;
        const float te  = alive ? t_entry : 0.0f;
        const float tex = alive ? t_exit  : 0.0f;

        float x = __fadd_rn(x0, __fmul_rn(te, dx));
        float y = __fadd_rn(y0, __fmul_rn(te, dy));
        int i = (int)fminf(fmaxf(rintf(__fadd_rn(x, 47.5f)), 0.0f), 95.0f);
        int j = (int)fminf(fmaxf(rintf(__fadd_rn(y, 47.5f)), 0.0f), 95.0f);
        float t = te;

        const bool okx = fabsf(dx) > EPSf;
        const bool oky = fabsf(dy) > EPSf;
        // reciprocal-mul instead of per-step IEEE div: <=2 ulp vs reference
        // (validated R2-R5: absmax stayed 0.25 vs 1.18 threshold).
        const float inv_dx = okx ? __fdiv_rn(1.0f, dx) : 0.0f;
        const float inv_dy = oky ? __fdiv_rn(1.0f, dy) : 0.0f;
        const float wscale = __fdiv_rn(DIAG, fmaxf(fabsf(dx) + fabsf(dy), EPSf));
        const float tex_m_eps = __fadd_rn(tex, -EPSf);
        // xn = (fi±0.5)-47.5 == fi + cx exactly (multiples of 0.5, |.|<144)
        const float cx = (dx > 0.0f) ? -47.0f : -48.0f;
        const float cy = (dy > 0.0f) ? -47.0f : -48.0f;
        const int   si = (dx > 0.0f) ? 1 : -1;   // dx==0 -> never selected
        const int   sj = (dy > 0.0f) ? 1 : -1;   // dy==0 -> never selected

        int n = 0;
        for (int step = 0; step < NSTEPS; ++step) {
            const bool valid = alive && (t < tex_m_eps);
            if (!__ballot(valid)) break;   // all 64 rays of the tile done
            if (valid) {
                const float txc = okx ? __fmul_rn(((float)i + cx) - x, inv_dx) : INF;
                const float tyc = oky ? __fmul_rn(((float)j + cy) - y, inv_dy) : INF;
                const float dt  = fminf(fminf(txc, tyc), __fadd_rn(tex, -t));
                const float seg = fmaxf(0.0f, __fmul_rn(dt, wscale));

                float2 e;
                e.x = __int_as_float((i * NH + j) * (ND * 4));  // BYTE offset
                e.y = seg;
                sE[rl][n] = e;
                ++n;

                const int i_n = i + ((txc <= tyc) ? si : 0);
                const int j_n = j + ((tyc <= txc) ? sj : 0);
                const bool inb = (i_n >= 0) && (i_n < NW) && (j_n >= 0) && (j_n < NH);
                x = __fadd_rn(x, __fmul_rn(dx, dt));
                y = __fadd_rn(y, __fmul_rn(dy, dt));
                t = __fadd_rn(t, dt);
                i = i_n; j = j_n;
                alive = inb;
            }
        }
        // pad to multiple of 8 with zero-weight entries (no gather tail loop)
        const int n8 = (n + 7) & ~7;                 // <= 200 <= NSP_L-1
        for (int p = n; p < n8; ++p) {
            float2 z; z.x = __int_as_float(0); z.y = 0.0f;
            sE[rl][p] = z;
        }
        counts[ray] = n8;                            // coalesced dword stores
    }
    __syncthreads();

    // ---- copy LDS -> global, ray-contiguous. Wave w copies rows w, w+8, ...
    // LDS read: lane k reads sE[r][base+k] -> banks 2k mod 32 = 2-way (free).
    // Global write: 512 B contiguous per iteration (fully coalesced).
    const int wid  = tid >> 6;
    const int lane = tid & 63;
    for (int r = wid; r < TTILE; r += 8) {
        const float2* __restrict__ src = &sE[r][0];
        float2* __restrict__ dst = ents + (size_t)(tile * TTILE + r) * GSTRIDE;
        for (int p = lane; p < NSP_L; p += 64)
            dst[p] = src[p];
    }
}

// ---------------------------------------------------------------------------
// Kernel B: gather. One wave per ray (lane = v). Entries are wave-uniform ->
// scalar loads (s_load_dwordx4) into SGPRs, software-pipelined one batch
// ahead; weight stays SGPR (v_fmac src0); vol address = SGPR base + fixed
// v*4 VGPR offset -> ~1 VALU + 1 VMEM per entry, zero LDS, tiny VGPR use.
// ---------------------------------------------------------------------------
__global__ __launch_bounds__(256)
void gather_kernel(const float* __restrict__ vol,
                   const float2* __restrict__ ents,
                   const int* __restrict__ counts,
                   float* __restrict__ out)
{
    // wave-uniform ray index, forced into an SGPR
    const int ray = __builtin_amdgcn_readfirstlane((blockIdx.x << 2) + (threadIdx.x >> 6));
    const int v   = threadIdx.x & 63;

    const int cnt8 = counts[ray];                      // scalar load, multiple of 8
    const float4* __restrict__ e4 = (const float4*)(ents + (size_t)ray * GSTRIDE);
    const char*   __restrict__ vb = (const char*)vol;

    // prefetch batch 0 (harmless garbage if cnt8 == 0: loop never runs)
    float4 pA = e4[0], pB = e4[1], pC = e4[2], pD = e4[3];

    float a0 = 0.0f, a1 = 0.0f, a2 = 0.0f, a3 = 0.0f;
    for (int n = 0; n < cnt8; n += 8) {
        // prefetch next batch (clamped -> branchless; re-reads last batch at end)
        const int qn = (n + 8 < cnt8) ? ((n >> 1) + 4) : (n >> 1);
        const float4 nA = e4[qn + 0], nB = e4[qn + 1], nC = e4[qn + 2], nD = e4[qn + 3];

        const float v0 = *(const float*)(vb + __float_as_int(pA.x) + (size_t)4 * v);
        const float v1 = *(const float*)(vb + __float_as_int(pA.z) + (size_t)4 * v);
        const float v2 = *(const float*)(vb + __float_as_int(pB.x) + (size_t)4 * v);
        const float v3 = *(const float*)(vb + __float_as_int(pB.z) + (size_t)4 * v);
        const float v4_ = *(const float*)(vb + __float_as_int(pC.x) + (size_t)4 * v);
        const float v5 = *(const float*)(vb + __float_as_int(pC.z) + (size_t)4 * v);
        const float v6 = *(const float*)(vb + __float_as_int(pD.x) + (size_t)4 * v);
        const float v7 = *(const float*)(vb + __float_as_int(pD.z) + (size_t)4 * v);

        a0 = fmaf(pA.y, v0, a0);
        a1 = fmaf(pA.w, v1, a1);
        a2 = fmaf(pB.y, v2, a2);
        a3 = fmaf(pB.w, v3, a3);
        a0 = fmaf(pC.y, v4_, a0);
        a1 = fmaf(pC.w, v5, a1);
        a2 = fmaf(pD.y, v6, a2);
        a3 = fmaf(pD.w, v7, a3);

        pA = nA; pB = nB; pC = nC; pD = nD;
    }
    const float acc = (a0 + a1) + (a2 + a3);

    const int a = ray / NU;
    const int u = ray - a * NU;
    out[(u * NA + a) * NV + v] = acc;   // coalesced 256 B store
}

// ---------------------------------------------------------------------------
// Fallback: proven single-kernel version (used only if ws_size is too small).
// ---------------------------------------------------------------------------
__global__ __launch_bounds__(64)
void siddon_fwd_kernel(const float* __restrict__ vol, float* __restrict__ out)
{
    const int ray = blockIdx.x;
    const int a   = ray / NU;
    const int u   = ray - a * NU;
    const int v   = threadIdx.x;

    const float EPSf = 1e-12f;
    const float INF  = __builtin_inff();
    const float DIAG = 1.41421356237309514547f;

    const float ang = (float)a * (float)(3.14159265358979323846 / 90.0);
    const float dx = (float)cos((double)ang);
    const float dy = (float)sin((double)ang);
    const float uu = (float)u - 47.5f;
    const float x0 = __fmul_rn(-uu, dy);
    const float y0 = __fmul_rn( uu, dx);

    const float xmin = -47.5f, xmax = 47.5f;
    const float ymin = -47.5f, ymax = 47.5f;

    float tx0, tx1;
    {
        const bool par = fabsf(dx) < EPSf;
        const float safe = par ? 1.0f : dx;
        const float t0 = __fdiv_rn(xmin - x0, safe);
        const float t1 = __fdiv_rn(xmax - x0, safe);
        const float lo = fminf(t0, t1), hi = fmaxf(t0, t1);
        const bool inside = (x0 >= xmin) && (x0 <= xmax);
        tx0 = par ? (inside ? -INF : INF) : lo;
        tx1 = par ? (inside ?  INF : -INF) : hi;
    }
    float ty0, ty1;
    {
        const bool par = fabsf(dy) < EPSf;
        const float safe = par ? 1.0f : dy;
        const float t0 = __fdiv_rn(ymin - y0, safe);
        const float t1 = __fdiv_rn(ymax - y0, safe);
        const float lo = fminf(t0, t1), hi = fmaxf(t0, t1);
        const bool inside = (y0 >= ymin) && (y0 <= ymax);
        ty0 = par ? (inside ? -INF : INF) : lo;
        ty1 = par ? (inside ?  INF : -INF) : hi;
    }

    const float t_entry = fmaxf(tx0, ty0);
    const float t_exit  = fminf(tx1, ty1);
    bool  alive = t_entry < t_exit;
    const float te  = alive ? t_entry : 0.0f;
    const float tex = alive ? t_exit  : 0.0f;

    float x = __fadd_rn(x0, __fmul_rn(te, dx));
    float y = __fadd_rn(y0, __fmul_rn(te, dy));
    int i = (int)fminf(fmaxf(rintf(__fadd_rn(x, 47.5f)), 0.0f), 95.0f);
    int j = (int)fminf(fmaxf(rintf(__fadd_rn(y, 47.5f)), 0.0f), 95.0f);
    float t = te;

    const float inv_sum = fmaxf(fabsf(dx) + fabsf(dy), EPSf);

    float acc = 0.0f;
    const float* __restrict__ volv = vol + v;

    for (int n = 0; n < NSTEPS; ++n) {
        const bool valid = alive && (t < __fadd_rn(tex, -EPSf));
        if (!valid) break;

        const float fi = (float)i, fj = (float)j;
        const float xn = (dx > 0.0f) ? (fi + 0.5f) - 47.5f
                       : (dx < 0.0f) ? (fi - 0.5f) - 47.5f : INF;
        const float yn = (dy > 0.0f) ? (fj + 0.5f) - 47.5f
                       : (dy < 0.0f) ? (fj - 0.5f) - 47.5f : INF;
        const float txc = (fabsf(dx) > EPSf) ? __fdiv_rn(xn - x, dx) : INF;
        const float tyc = (fabsf(dy) > EPSf) ? __fdiv_rn(yn - y, dy) : INF;
        const float dt  = fminf(fminf(txc, tyc), __fadd_rn(tex, -t));
        const float seg = fmaxf(0.0f, __fdiv_rn(__fmul_rn(dt, DIAG), inv_sum));

        acc = fmaf(seg, volv[(i * NH + j) * ND], acc);

        const int i_n = i + ((txc <= tyc) ? ((dx > 0.0f) ? 1 : -1) : 0);
        const int j_n = j + ((tyc <= txc) ? ((dy > 0.0f) ? 1 : -1) : 0);
        const bool inb = (i_n >= 0) && (i_n < NW) && (j_n >= 0) && (j_n < NH);
        x = __fadd_rn(x, __fmul_rn(dx, dt));
        y = __fadd_rn(y, __fmul_rn(dy, dt));
        t = __fadd_rn(t, dt);
        i = i_n; j = j_n;
        alive = inb;
    }

    out[(u * NA + a) * NV + v] = acc;
}

extern "C" void kernel_launch(void* const* d_in, const int* in_sizes, int n_in,
                              void* d_out, int out_size, void* d_ws, size_t ws_size,
                              hipStream_t stream) {
    const float* vol = (const float*)d_in[0];
    float* out = (float*)d_out;

    const size_t ents_bytes   = (size_t)NRAY * GSTRIDE * sizeof(float2); // 14.38 MB
    const size_t counts_bytes = (size_t)NRAY * sizeof(int);
    if (ws_size >= ents_bytes + counts_bytes) {
        float2* ents   = (float2*)d_ws;
        int*    counts = (int*)((char*)d_ws + ents_bytes);
        hipLaunchKernelGGL(trace_kernel, dim3(NTBLK), dim3(512), 0, stream,
                           ents, counts);
        hipLaunchKernelGGL(gather_kernel, dim3(NGBLK), dim3(256), 0, stream,
                           vol, ents, counts, out);
    } else {
        hipLaunchKernelGGL(siddon_fwd_kernel, dim3(NRAY), dim3(64), 0, stream,
                           vol, out);
    }
}

// Round 7
// 90.989 us; speedup vs baseline: 1.0990x; 1.0990x over previous
//
#include <hip/hip_runtime.h>
#include <math.h>

// Problem constants (from reference):
//   vol: (B=1, C=1, W=96, H=96, D=64) float32, row-major -> vol[(x*96+y)*64+z]
//   out: (B,C,U=96,A=90,V=64) float32 -> out[(u*90+a)*64+v]
//   k[v] = v identically (V=D=64, SV=SD=1), so depth slice index == lane group.
namespace {
constexpr int NA = 90, NU = 96, NV = 64, NW = 96, NH = 96, ND = 64;
constexpr int NRAY   = NA * NU;      // 8640
constexpr int NSTEPS = NH + NW + 2;  // 194
constexpr int ROW    = 209;          // LDS row: >= 208 (194 padded to x16);
                                     // 209 odd -> trace writes conflict-free
constexpr int TILE   = 8;            // rays per block = waves per block
constexpr int NBLK   = NRAY / TILE;  // 1080 blocks (~4.2/CU)
}

// Fused Siddon projector, quad-row gather:
//   Phase 1 (wave 0, lanes 0..7): trace 8 rays -> LDS SoA (offset[], weight[]),
//     zero-padded to a multiple of 16 entries.
//   Phase 2 (8 waves, wave = ray): lane L handles row r=L>>4 of each entry
//     quad, chunk sub=L&15 -> ONE global_load_dwordx4 per 4 entries fetches
//     four 256B vol rows (R3-R6 post-mortem: every shape with one wave-load
//     per entry landed at ~45-50us => ~6750 loads/CU x ~15cyc VMEM-instr cost
//     is the binder; this cuts instruction count 4x at identical bytes).
//   Epilogue: xor16/xor32 shuffle-reduce across row groups, lanes 0..15 store
//     one float4 each (256B coalesced).
__global__ __launch_bounds__(512)
void siddon_fused(const float* __restrict__ vol, float* __restrict__ out)
{
    __shared__ int   sOff[TILE * ROW];   // BYTE offset of vol row
    __shared__ float sW  [TILE * ROW];   // segment weight
    __shared__ int   sCnt[TILE];         // entry count padded to multiple of 16

    const int tid  = threadIdx.x;
    const int tile = blockIdx.x;

    // ---------------- Phase 1: trace (wave 0, lanes 0..TILE-1) ----------------
    if (tid < 64) {
        const int  rl     = tid;
        const bool tracer = rl < TILE;            // lanes 8..63 ride along dead
        const int  ray    = tile * TILE + (tracer ? rl : 0);
        const int  a = ray / NU;
        const int  u = ray - a * NU;

        const float EPSf = 1e-12f;
        const float INF  = __builtin_inff();
        const float DIAG = 1.41421356237309514547f;

        const float ang = (float)a * (float)(3.14159265358979323846 / 90.0);
        const float dx = (float)cos((double)ang);
        const float dy = (float)sin((double)ang);
        const float uu = (float)u - 47.5f;
        const float x0 = __fmul_rn(-uu, dy);
        const float y0 = __fmul_rn( uu, dx);

        const float xmin = -47.5f, xmax = 47.5f;
        const float ymin = -47.5f, ymax = 47.5f;

        float tx0, tx1;
        {
            const bool par = fabsf(dx) < EPSf;
            const float safe = par ? 1.0f : dx;
            const float t0 = __fdiv_rn(xmin - x0, safe);
            const float t1 = __fdiv_rn(xmax - x0, safe);
            const float lo = fminf(t0, t1), hi = fmaxf(t0, t1);
            const bool inside = (x0 >= xmin) && (x0 <= xmax);
            tx0 = par ? (inside ? -INF : INF) : lo;
            tx1 = par ? (inside ?  INF : -INF) : hi;
        }
        float ty0, ty1;
        {
            const bool par = fabsf(dy) < EPSf;
            const float safe = par ? 1.0f : dy;
            const float t0 = __fdiv_rn(ymin - y0, safe);
            const float t1 = __fdiv_rn(ymax - y0, safe);
            const float lo = fminf(t0, t1), hi = fmaxf(t0, t1);
            const bool inside = (y0 >= ymin) && (y0 <= ymax);
            ty0 = par ? (inside ? -INF : INF) : lo;
            ty1 = par ? (inside ?  INF : -INF) : hi;
        }

        const float t_entry = fmaxf(tx0, ty0);
        const float t_exit  = fminf(tx1, ty1);
        bool  alive = tracer && (t_entry < t_exit);
        const float te  = (t_entry < t_exit) ? t_entry : 0.0f;
        const float tex = (t_entry < t_exit) ? t_exit  : 0.0f;

        float x = __fadd_rn(x0, __fmul_rn(te, dx));
        float y = __fadd_rn(y0, __fmul_rn(te, dy));
        int i = (int)fminf(fmaxf(rintf(__fadd_rn(x, 47.5f)), 0.0f), 95.0f);
        int j = (int)fminf(fmaxf(rintf(__fadd_rn(y, 47.5f)), 0.0f), 95.0f);
        float t = te;

        const bool okx = fabsf(dx) > EPSf;
        const bool oky = fabsf(dy) > EPSf;
        // reciprocal-mul instead of per-step IEEE div: <=2 ulp vs reference
        // (validated R2-R6: absmax stayed 0.25 vs 1.18 threshold).
        const float inv_dx = okx ? __fdiv_rn(1.0f, dx) : 0.0f;
        const float inv_dy = oky ? __fdiv_rn(1.0f, dy) : 0.0f;
        const float wscale = __fdiv_rn(DIAG, fmaxf(fabsf(dx) + fabsf(dy), EPSf));
        const float tex_m_eps = __fadd_rn(tex, -EPSf);
        // next-boundary coords, tracked incrementally (+-1.0 exact: |.|<150<2^23)
        const float cx = (dx > 0.0f) ? -47.0f : -48.0f;
        const float cy = (dy > 0.0f) ? -47.0f : -48.0f;
        float xn = (float)i + cx;      // == (i +- 0.5) - 47.5 exactly
        float yn = (float)j + cy;
        const float sxf = (dx > 0.0f) ? 1.0f : -1.0f;
        const float syf = (dy > 0.0f) ? 1.0f : -1.0f;
        const int   si  = (dx > 0.0f) ? 1 : -1;   // dx==0 -> never selected
        const int   sj  = (dy > 0.0f) ? 1 : -1;   // dy==0 -> never selected

        int n = 0;
        for (int step = 0; step < NSTEPS; ++step) {
            const bool valid = alive && (t < tex_m_eps);
            if (!__ballot(valid)) break;   // all 8 rays of the tile done
            if (valid) {
                const float txc = okx ? __fmul_rn(xn - x, inv_dx) : INF;
                const float tyc = oky ? __fmul_rn(yn - y, inv_dy) : INF;
                const float dt  = fminf(fminf(txc, tyc), __fadd_rn(tex, -t));
                const float seg = fmaxf(0.0f, __fmul_rn(dt, wscale));

                sOff[rl * ROW + n] = (i * NH + j) << 8;   // BYTE offset into vol
                sW  [rl * ROW + n] = seg;
                ++n;

                const bool cndx = (txc <= tyc);
                const bool cndy = (tyc <= txc);
                const int i_n = i + (cndx ? si : 0);
                const int j_n = j + (cndy ? sj : 0);
                xn += cndx ? sxf : 0.0f;
                yn += cndy ? syf : 0.0f;
                const bool inb = ((unsigned)i_n < (unsigned)NW) &&
                                 ((unsigned)j_n < (unsigned)NH);
                x = __fadd_rn(x, __fmul_rn(dx, dt));
                y = __fadd_rn(y, __fmul_rn(dy, dt));
                t = __fadd_rn(t, dt);
                i = i_n; j = j_n;
                alive = inb;
            }
        }
        if (tracer) {
            const int n16 = (n + 15) & ~15;        // <= 208 <= ROW-1
            for (int p = n; p < n16; ++p) {        // zero-weight pad
                sOff[rl * ROW + p] = 0;
                sW  [rl * ROW + p] = 0.0f;
            }
            sCnt[rl] = n16;
        }
    }
    __syncthreads();

    // ---------------- Phase 2: gather (wave w -> ray w) ----------------
    const int wid  = tid >> 6;         // 0..7 == ray-in-tile
    const int lane = tid & 63;
    const int r    = lane >> 4;        // row-in-quad 0..3
    const int sub  = lane & 15;        // 16B chunk within the 256B row
    const int subOff = sub << 4;

    const int cnt = sCnt[wid];
    const int*   __restrict__ oRow = &sOff[wid * ROW + r];  // entry n+r at [n]
    const float* __restrict__ wRow = &sW  [wid * ROW + r];
    const char*  __restrict__ vb   = (const char*)vol;

    float4 aA = {0,0,0,0}, aB = {0,0,0,0}, aC = {0,0,0,0}, aD = {0,0,0,0};
    for (int n = 0; n < cnt; n += 16) {
        const int o0 = oRow[n];        // 4-address LDS broadcast (conflict-free)
        const int o1 = oRow[n + 4];
        const int o2 = oRow[n + 8];
        const int o3 = oRow[n + 12];
        const float w0 = wRow[n];
        const float w1 = wRow[n + 4];
        const float w2 = wRow[n + 8];
        const float w3 = wRow[n + 12];
        const float4 v0 = *(const float4*)(vb + (o0 + subOff));  // 4 rows / instr
        const float4 v1 = *(const float4*)(vb + (o1 + subOff));
        const float4 v2 = *(const float4*)(vb + (o2 + subOff));
        const float4 v3 = *(const float4*)(vb + (o3 + subOff));
        aA.x = fmaf(w0, v0.x, aA.x); aA.y = fmaf(w0, v0.y, aA.y);
        aA.z = fmaf(w0, v0.z, aA.z); aA.w = fmaf(w0, v0.w, aA.w);
        aB.x = fmaf(w1, v1.x, aB.x); aB.y = fmaf(w1, v1.y, aB.y);
        aB.z = fmaf(w1, v1.z, aB.z); aB.w = fmaf(w1, v1.w, aB.w);
        aC.x = fmaf(w2, v2.x, aC.x); aC.y = fmaf(w2, v2.y, aC.y);
        aC.z = fmaf(w2, v2.z, aC.z); aC.w = fmaf(w2, v2.w, aC.w);
        aD.x = fmaf(w3, v3.x, aD.x); aD.y = fmaf(w3, v3.y, aD.y);
        aD.z = fmaf(w3, v3.z, aD.z); aD.w = fmaf(w3, v3.w, aD.w);
    }
    float sx = (aA.x + aB.x) + (aC.x + aD.x);
    float sy = (aA.y + aB.y) + (aC.y + aD.y);
    float sz = (aA.z + aB.z) + (aC.z + aD.z);
    float sw = (aA.w + aB.w) + (aC.w + aD.w);

    // reduce across the 4 row groups: lanes {sub, 16+sub, 32+sub, 48+sub}
    sx += __shfl_xor(sx, 16, 64);  sy += __shfl_xor(sy, 16, 64);
    sz += __shfl_xor(sz, 16, 64);  sw += __shfl_xor(sw, 16, 64);
    sx += __shfl_xor(sx, 32, 64);  sy += __shfl_xor(sy, 32, 64);
    sz += __shfl_xor(sz, 32, 64);  sw += __shfl_xor(sw, 32, 64);

    if (lane < 16) {
        const int ray = tile * TILE + wid;
        const int a = ray / NU;
        const int u = ray - a * NU;
        float4 res; res.x = sx; res.y = sy; res.z = sz; res.w = sw;
        *(float4*)(out + (u * NA + a) * NV + (sub << 2)) = res;  // 256B coalesced
    }
}

extern "C" void kernel_launch(void* const* d_in, const int* in_sizes, int n_in,
                              void* d_out, int out_size, void* d_ws, size_t ws_size,
                              hipStream_t stream) {
    const float* vol = (const float*)d_in[0];
    float* out = (float*)d_out;
    hipLaunchKernelGGL(siddon_fused, dim3(NBLK), dim3(512), 0, stream, vol, out);
}